// Round 5
// baseline (933.341 us; speedup 1.0000x reference)
//
#include <hip/hip_runtime.h>
#include <hip/hip_bf16.h>
#include <stdint.h>

#define NTOT 131072
#define NSEG 16
#define EPSV 1e-5f

typedef __attribute__((ext_vector_type(8))) short bf16x8;
typedef __attribute__((ext_vector_type(4))) float f32x4;

struct Args {
  const float* x; const int* npts;
  const float *W1,*b1,*g1,*be1,*m1,*v1;
  const float *W2,*b2,*g2,*be2,*m2,*v2;
  const float *W3,*b3,*g3,*be3,*m3,*v3;
  const float *W4,*b4,*g4,*be4,*m4,*v4;
  int* offs;
  float *a1,*c1,*a2,*c2,*a3,*c3,*a4,*c4;
  unsigned int *gkeys,*vkeys;
  unsigned short *w2b;
  unsigned short *w3p;     // [2 Mt][8 ks][4 kgrel][256 cout][8]   (f-part of W3, k=256..512)
  unsigned short *w4p;     // [4 Mt][16 ks][4 kgrel][256 cout][8]
  unsigned short *fbufp;   // [4096 chunk][32 kg][32 pt][8]  (f acts, 256 ch, 32-pt chunks)
  float* cseg;             // [16][512] = W3[:, :256] @ gs(seg)
  float* out;
};

__device__ inline unsigned int f2key(float f){ unsigned u=__float_as_uint(f); return (u&0x80000000u)? ~u : (u|0x80000000u); }
__device__ inline float key2f(unsigned k){ unsigned u=(k&0x80000000u)? (k^0x80000000u) : ~k; return __uint_as_float(u); }
__device__ inline unsigned short f2bf(float f){ __hip_bfloat16 h=__float2bfloat16(f); return *(unsigned short*)&h; }

__device__ inline void gl16(const void* g, void* l){
  __builtin_amdgcn_global_load_lds((const __attribute__((address_space(1))) unsigned int*)g,
                                   (__attribute__((address_space(3))) unsigned int*)l, 16, 0, 0);
}

// ---------------- setup ----------------
__global__ void k_setup(Args A){
  int tid = threadIdx.x;
  if (tid==0){ int s=0; A.offs[0]=0; for (int i=0;i<NSEG;i++){ s+=A.npts[i]; A.offs[i+1]=s; } }
  for (int c=tid;c<128;c+=256){ float a=A.g1[c]*rsqrtf(A.v1[c]+EPSV); A.a1[c]=a; A.c1[c]=A.be1[c]+a*(A.b1[c]-A.m1[c]); }
  for (int c=tid;c<256;c+=256){ float a=A.g2[c]*rsqrtf(A.v2[c]+EPSV); A.a2[c]=a; A.c2[c]=A.be2[c]+a*(A.b2[c]-A.m2[c]); }
  for (int c=tid;c<512;c+=256){ float a=A.g3[c]*rsqrtf(A.v3[c]+EPSV); A.a3[c]=a; A.c3[c]=A.be3[c]+a*(A.b3[c]-A.m3[c]); }
  for (int c=tid;c<1024;c+=256){ float a=A.g4[c]*rsqrtf(A.v4[c]+EPSV); A.a4[c]=a; A.c4[c]=A.be4[c]+a*(A.b4[c]-A.m4[c]); }
  for (int i=tid;i<NSEG*256;i+=256)  A.gkeys[i]=0u;
  for (int i=tid;i<NSEG*1024;i+=256) A.vkeys[i]=0u;
}

// ---------------- weights fp32 -> bf16, K-tile-chunk packed (unchanged from round 4) ----------------
// w3p entry o: o = Mt<<16 | ks<<13 | kgrel<<11 | cout<<3 | j  -> W3[(Mt*256+cout)*512 + 256 + ks*32+kgrel*8+j]
// w4p entry o: o = Mt<<17 | ks<<13 | kgrel<<11 | cout<<3 | j  -> W4[(Mt*256+cout)*512 + ks*32+kgrel*8+j]
__global__ void k_conv(Args A){
  const int n1=256*128;        // 32768
  const int n2=131072;
  const int n3=524288;
  for (int i = blockIdx.x*256+threadIdx.x; i < n1+n2+n3; i += gridDim.x*256){
    if (i<n1) A.w2b[i]=f2bf(A.W2[i]);
    else if (i<n1+n2){
      int o=i-n1; int j=o&7, cout=(o>>3)&255, kgrel=(o>>11)&3, ks=(o>>13)&7, cg=(o>>16)&1;
      A.w3p[o]=f2bf(A.W3[(size_t)(cg*256+cout)*512 + 256 + ks*32 + kgrel*8 + j]);
    } else {
      int o=i-n1-n2; int j=o&7, cout=(o>>3)&255, kgrel=(o>>11)&3, ks=(o>>13)&15, cg=(o>>17)&3;
      A.w4p[o]=f2bf(A.W4[(size_t)(cg*256+cout)*512 + ks*32 + kgrel*8 + j]);
    }
  }
}

// ---------------- L1 (VALU) + L2 (MFMA) + BN -> fbufp (32-pt chunk packed) + gkeys ----------------
__global__ __launch_bounds__(256) void k_l12(Args A){
  __shared__ float w1s[384], a1s[128], c1s[128], a2s[256], c2s[256];
  __shared__ float xs[3][64];
  __shared__ int offs_s[NSEG+1], segp[64];
  __shared__ unsigned short hs[16*64*8];
  int tid=threadIdx.x, pt0=blockIdx.x*64;
  for (int i=tid;i<384;i+=256) w1s[i]=A.W1[i];
  if (tid<128){ a1s[tid]=A.a1[tid]; c1s[tid]=A.c1[tid]; }
  a2s[tid]=A.a2[tid]; c2s[tid]=A.c2[tid];
  if (tid<=NSEG) offs_s[tid]=A.offs[tid];
  if (tid<64){ xs[0][tid]=A.x[pt0+tid]; xs[1][tid]=A.x[NTOT+pt0+tid]; xs[2][tid]=A.x[2*NTOT+pt0+tid]; }
  __syncthreads();
  if (tid<64){ int gp=pt0+tid, s=0; while (gp>=offs_s[s+1]) s++; segp[tid]=s; }
  for (int pair=tid; pair<1024; pair+=256){
    int pt=pair&63, kc=pair>>6;
    float x0=xs[0][pt], x1=xs[1][pt], x2=xs[2][pt];
    unsigned short us[8];
    #pragma unroll
    for (int j=0;j<8;j++){
      int cin=kc*8+j;
      float v = fmaf(w1s[cin*3],x0, fmaf(w1s[cin*3+1],x1, w1s[cin*3+2]*x2));
      v = fmaxf(fmaf(a1s[cin],v,c1s[cin]), 0.f);
      us[j]=f2bf(v);
    }
    uint4 pk;
    pk.x=(unsigned)us[0]|((unsigned)us[1]<<16); pk.y=(unsigned)us[2]|((unsigned)us[3]<<16);
    pk.z=(unsigned)us[4]|((unsigned)us[5]<<16); pk.w=(unsigned)us[6]|((unsigned)us[7]<<16);
    *(uint4*)(&hs[(kc*64+pt)*8]) = pk;
  }
  __syncthreads();
  int lane=tid&63, wv=tid>>6, quad=lane>>4, l16=lane&15;
  int m0=wv*64;
  f32x4 acc[4][4];
  for (int a=0;a<4;a++)
    for (int b=0;b<4;b++)
      acc[a][b]=(f32x4){0.f,0.f,0.f,0.f};
  #pragma unroll
  for (int ks=0; ks<4; ++ks){
    bf16x8 bfr[4];
    #pragma unroll
    for (int nt=0; nt<4; ++nt) bfr[nt]=*(bf16x8*)(&hs[((ks*4+quad)*64 + nt*16 + l16)*8]);
    #pragma unroll
    for (int mt=0; mt<4; ++mt){
      bf16x8 afr = *(const bf16x8*)(&A.w2b[(m0+mt*16+l16)*128 + ks*32 + quad*8]);
      #pragma unroll
      for (int nt=0; nt<4; ++nt)
        acc[mt][nt]=__builtin_amdgcn_mfma_f32_16x16x32_bf16(afr, bfr[nt], acc[mt][nt], 0,0,0);
    }
  }
  bool uni = (segp[0]==segp[63]); int seg0=segp[0];
  #pragma unroll
  for (int mt=0;mt<4;++mt){
    int cout0=m0+mt*16+quad*4;
    int kg=cout0>>3, sub=cout0&7;
    float fv[4][4];
    #pragma unroll
    for (int nt=0;nt<4;++nt)
      #pragma unroll
      for (int r=0;r<4;++r)
        fv[nt][r]=fmaf(a2s[cout0+r], acc[mt][nt][r], c2s[cout0+r]);
    #pragma unroll
    for (int nt=0;nt<4;++nt){
      int ptl=nt*16+l16;
      uint2 pk;
      pk.x=(unsigned)f2bf(fv[nt][0])|((unsigned)f2bf(fv[nt][1])<<16);
      pk.y=(unsigned)f2bf(fv[nt][2])|((unsigned)f2bf(fv[nt][3])<<16);
      size_t o = (size_t)(blockIdx.x*2 + (nt>>1))*8192 + (size_t)(kg*256 + ((nt&1)*16+l16)*8 + sub);
      *(uint2*)&A.fbufp[o] = pk;
    }
    #pragma unroll
    for (int r=0;r<4;++r){
      if (uni){
        float mv=fmaxf(fmaxf(fv[0][r],fv[1][r]),fmaxf(fv[2][r],fv[3][r]));
        #pragma unroll
        for (int off=8;off>=1;off>>=1) mv=fmaxf(mv, __shfl_xor(mv,off));
        if (l16==0) atomicMax(&A.gkeys[seg0*256+cout0+r], f2key(mv));
      } else {
        #pragma unroll
        for (int nt=0;nt<4;++nt)
          atomicMax(&A.gkeys[segp[nt*16+l16]*256+cout0+r], f2key(fv[nt][r]));
      }
    }
  }
}

// ---------------- cseg[seg][cout] = W3[:, :256] @ gs(seg) ----------------
__global__ void k_cseg(Args A){
  int seg = blockIdx.x>>1; int cout = (blockIdx.x&1)*256 + threadIdx.x;
  __shared__ float gs[256];
  gs[threadIdx.x] = key2f(A.gkeys[seg*256+threadIdx.x]);
  __syncthreads();
  const float* wrow = A.W3 + (size_t)cout*512;
  float s=0.f;
  #pragma unroll 8
  for (int k=0;k<256;k++) s = fmaf(wrow[k], gs[k], s);
  A.cseg[seg*512+cout]=s;
}

// ---------------- fused L3+L4: h3 lives in LDS, weights streamed from L2, segmax-only output ----------------
// 1024 blocks x 512 thr (8 waves). Block = 128 pts.
// Phase 1: h3[512 ch][128 pt] = relu(bn3(W3f @ f + cseg)) -> LDS (f staged in 4x 32-pt chunks).
// Phase 2: h4 = bn4(W4 @ h3), fused segmax (atomics only; no global output traffic).
__global__ __launch_bounds__(512,1) void k_l34(Args A){
  __shared__ unsigned short h3s[65536];   // [64 kg][128 pt][8] = 128 KB
  __shared__ unsigned short fstg[8192];   // [32 kg][32 pt][8]  = 16 KB
  __shared__ int offs_s[NSEG+1];
  int blk=blockIdx.x;
  int tid=threadIdx.x, lane=tid&63, wv=tid>>6, quad=lane>>4, l16=lane&15;
  if (tid<=NSEG) offs_s[tid]=A.offs[tid];
  int c0=wv*64;                            // wave's 64 h3-couts in phase 1

  // ---- phase 1 ----
  for (int chunk=0;chunk<4;++chunk){
    const char* src=(const char*)A.fbufp + ((size_t)(blk*4+chunk))*16384;
    gl16(src + wv*2048 + lane*16, (char*)fstg + wv*2048);
    gl16(src + wv*2048 + 1024 + lane*16, (char*)fstg + wv*2048 + 1024);
    __syncthreads();
    f32x4 acc1[4][2];
    #pragma unroll
    for (int mt=0;mt<4;++mt)
      #pragma unroll
      for (int nt=0;nt<2;++nt)
        acc1[mt][nt]=(f32x4){0.f,0.f,0.f,0.f};
    #pragma unroll
    for (int kk=0;kk<8;++kk){
      bf16x8 bfr[2], afr[4];
      #pragma unroll
      for (int nt=0;nt<2;++nt)
        bfr[nt]=*(const bf16x8*)(&fstg[((kk*4+quad)*32 + nt*16 + l16)*8]);
      #pragma unroll
      for (int mt=0;mt<4;++mt){
        int cout=c0+mt*16+l16;
        afr[mt]=*(const bf16x8*)(A.w3p + (size_t)((cout>>8)*65536 + kk*8192 + quad*2048 + (cout&255)*8));
      }
      __builtin_amdgcn_s_setprio(1);
      #pragma unroll
      for (int mt=0;mt<4;++mt)
        #pragma unroll
        for (int nt=0;nt<2;++nt)
          acc1[mt][nt]=__builtin_amdgcn_mfma_f32_16x16x32_bf16(afr[mt], bfr[nt], acc1[mt][nt], 0,0,0);
      __builtin_amdgcn_s_setprio(0);
    }
    // chunk epilogue: BN + ReLU + cseg add -> h3s
    int pt0c = blk*128 + chunk*32;
    int sBeg=0; while (pt0c >= offs_s[sBeg+1]) sBeg++;
    int sEnd=sBeg; while (pt0c+31 >= offs_s[sEnd+1]) sEnd++;
    bool uni=(sBeg==sEnd);
    int segl[2];
    if (!uni){
      #pragma unroll
      for (int nt=0;nt<2;++nt){ int gp=pt0c+nt*16+l16, ss=sBeg; while (gp>=offs_s[ss+1]) ss++; segl[nt]=ss; }
    }
    #pragma unroll
    for (int mt=0;mt<4;++mt){
      int cout0=c0+mt*16+quad*4;
      int kg3=cout0>>3, sub3=cout0&7;
      float sa[4],sc[4],csr[4];
      #pragma unroll
      for (int r=0;r<4;++r){ sa[r]=A.a3[cout0+r]; sc[r]=A.c3[cout0+r]; }
      if (uni){
        #pragma unroll
        for (int r=0;r<4;++r) csr[r]=A.cseg[sBeg*512+cout0+r];
      }
      #pragma unroll
      for (int nt=0;nt<2;++nt){
        int ptt=chunk*32+nt*16+l16;
        unsigned short us[4];
        #pragma unroll
        for (int r=0;r<4;++r){
          float cv = uni? csr[r] : A.cseg[segl[nt]*512+cout0+r];
          float hv = fmaxf(fmaf(sa[r], acc1[mt][nt][r]+cv, sc[r]), 0.f);
          us[r]=f2bf(hv);
        }
        uint2 pk;
        pk.x=(unsigned)us[0]|((unsigned)us[1]<<16);
        pk.y=(unsigned)us[2]|((unsigned)us[3]<<16);
        *(uint2*)&h3s[(size_t)((kg3*128+ptt)*8+sub3)] = pk;
      }
    }
    __syncthreads();
  }

  // ---- phase 2: h4 = bn4(W4 @ h3), fused segmax ----
  for (int ci=0;ci<2;++ci){
    int cc0=ci*512+c0;                     // wave's 64 h4-couts this pass
    f32x4 acc2[2][4][4];
    #pragma unroll
    for (int pi=0;pi<2;++pi)
      #pragma unroll
      for (int mt=0;mt<4;++mt)
        #pragma unroll
        for (int nt=0;nt<4;++nt)
          acc2[pi][mt][nt]=(f32x4){0.f,0.f,0.f,0.f};
    bf16x8 aF[2][4];
    #pragma unroll
    for (int mt=0;mt<4;++mt){
      int cout=cc0+mt*16+l16;
      aF[0][mt]=*(const bf16x8*)(A.w4p + (size_t)((cout>>8)*131072 + quad*2048 + (cout&255)*8));
    }
    #pragma unroll
    for (int kk=0;kk<16;++kk){
      const int cb=kk&1, nb=cb^1;
      if (kk<15){
        #pragma unroll
        for (int mt=0;mt<4;++mt){
          int cout=cc0+mt*16+l16;
          aF[nb][mt]=*(const bf16x8*)(A.w4p + (size_t)((cout>>8)*131072 + (kk+1)*8192 + quad*2048 + (cout&255)*8));
        }
      }
      bf16x8 b2[2][4];
      #pragma unroll
      for (int pi=0;pi<2;++pi)
        #pragma unroll
        for (int nt=0;nt<4;++nt)
          b2[pi][nt]=*(const bf16x8*)(&h3s[(size_t)(((kk*4+quad)*128 + pi*64 + nt*16 + l16)*8)]);
      __builtin_amdgcn_s_setprio(1);
      #pragma unroll
      for (int pi=0;pi<2;++pi)
        #pragma unroll
        for (int mt=0;mt<4;++mt)
          #pragma unroll
          for (int nt=0;nt<4;++nt)
            acc2[pi][mt][nt]=__builtin_amdgcn_mfma_f32_16x16x32_bf16(aF[cb][mt], b2[pi][nt], acc2[pi][mt][nt], 0,0,0);
      __builtin_amdgcn_s_setprio(0);
    }
    // epilogue: BN + fused segmax
    #pragma unroll
    for (int pi=0;pi<2;++pi){
      int pt0=blk*128+pi*64;
      int sBeg=0; while (pt0 >= offs_s[sBeg+1]) sBeg++;
      int sEnd=sBeg; while (pt0+63 >= offs_s[sEnd+1]) sEnd++;
      bool uni=(sBeg==sEnd);
      int segl[4];
      if (!uni){
        #pragma unroll
        for (int nt=0;nt<4;++nt){ int gp=pt0+nt*16+l16, ss=sBeg; while (gp>=offs_s[ss+1]) ss++; segl[nt]=ss; }
      }
      #pragma unroll
      for (int mt=0;mt<4;++mt){
        int cout0=cc0+mt*16+quad*4;
        #pragma unroll
        for (int r=0;r<4;++r){
          int cout=cout0+r;
          float sa=A.a4[cout], sc=A.c4[cout];
          float mv=-3.4e38f;
          #pragma unroll
          for (int nt=0;nt<4;++nt){
            float fv=fmaf(sa, acc2[pi][mt][nt][r], sc);
            if (uni) mv=fmaxf(mv,fv);
            else atomicMax(&A.vkeys[segl[nt]*1024+cout], f2key(fv));
          }
          if (uni){
            #pragma unroll
            for (int off=8;off>=1;off>>=1) mv=fmaxf(mv, __shfl_xor(mv,off));
            if (l16==0) atomicMax(&A.vkeys[sBeg*1024+cout], f2key(mv));
          }
        }
      }
    }
  }
}

// ---------------- decode ----------------
__global__ void k_final(Args A){
  int i=blockIdx.x*256+threadIdx.x;
  if (i<NSEG*1024) A.out[i]=key2f(A.vkeys[i]);
}

extern "C" void kernel_launch(void* const* d_in, const int* in_sizes, int n_in,
                              void* d_out, int out_size, void* d_ws, size_t ws_size,
                              hipStream_t stream){
  Args A;
  A.x  =(const float*)d_in[0];  A.npts=(const int*)d_in[1];
  A.W1 =(const float*)d_in[2];  A.b1 =(const float*)d_in[3];
  A.g1 =(const float*)d_in[4];  A.be1=(const float*)d_in[5];
  A.m1 =(const float*)d_in[6];  A.v1 =(const float*)d_in[7];
  A.W2 =(const float*)d_in[8];  A.b2 =(const float*)d_in[9];
  A.g2 =(const float*)d_in[10]; A.be2=(const float*)d_in[11];
  A.m2 =(const float*)d_in[12]; A.v2 =(const float*)d_in[13];
  A.W3 =(const float*)d_in[14]; A.b3 =(const float*)d_in[15];
  A.g3 =(const float*)d_in[16]; A.be3=(const float*)d_in[17];
  A.m3 =(const float*)d_in[18]; A.v3 =(const float*)d_in[19];
  A.W4 =(const float*)d_in[20]; A.b4 =(const float*)d_in[21];
  A.g4 =(const float*)d_in[22]; A.be4=(const float*)d_in[23];
  A.m4 =(const float*)d_in[24]; A.v4 =(const float*)d_in[25];

  char* w=(char*)d_ws;
  auto alloc=[&](size_t b)->void*{ void* p=(void*)w; w += (b+255)&~(size_t)255; return p; };
  A.offs =(int*)alloc((NSEG+1)*4);
  A.a1=(float*)alloc(128*4);  A.c1=(float*)alloc(128*4);
  A.a2=(float*)alloc(256*4);  A.c2=(float*)alloc(256*4);
  A.a3=(float*)alloc(512*4);  A.c3=(float*)alloc(512*4);
  A.a4=(float*)alloc(1024*4); A.c4=(float*)alloc(1024*4);
  A.gkeys=(unsigned int*)alloc(NSEG*256*4);
  A.vkeys=(unsigned int*)alloc(NSEG*1024*4);
  A.cseg =(float*)alloc(NSEG*512*4);
  A.w2b=(unsigned short*)alloc(256*128*2);
  A.w3p=(unsigned short*)alloc(131072*2);
  A.w4p=(unsigned short*)alloc(524288*2);
  A.fbufp=(unsigned short*)alloc((size_t)4096*8192*2);   // 64 MB, 32-pt chunk packed
  A.out=(float*)d_out;

  k_setup<<<dim3(1),dim3(256),0,stream>>>(A);
  k_conv <<<dim3(2688),dim3(256),0,stream>>>(A);
  k_l12  <<<dim3(NTOT/64),dim3(256),0,stream>>>(A);
  k_cseg <<<dim3(32),dim3(256),0,stream>>>(A);
  k_l34  <<<dim3(1024),dim3(512),0,stream>>>(A);
  k_final<<<dim3(64),dim3(256),0,stream>>>(A);
}

// Round 6
// 804.787 us; speedup vs baseline: 1.1597x; 1.1597x over previous
//
#include <hip/hip_runtime.h>
#include <hip/hip_bf16.h>
#include <stdint.h>

#define NTOT 131072
#define NSEG 16
#define EPSV 1e-5f

typedef __attribute__((ext_vector_type(8))) short bf16x8;
typedef __attribute__((ext_vector_type(4))) float f32x4;

struct Args {
  const float* x; const int* npts;
  const float *W1,*b1,*g1,*be1,*m1,*v1;
  const float *W2,*b2,*g2,*be2,*m2,*v2;
  const float *W3,*b3,*g3,*be3,*m3,*v3;
  const float *W4,*b4,*g4,*be4,*m4,*v4;
  int* offs;
  float *a1,*c1,*a2,*c2,*a3,*c3,*a4,*c4;
  unsigned int *gkeys,*vkeys;
  unsigned short *w2b;
  unsigned short *w3p;     // [4 mtile][32 kgg][128 cout_rel][8]   (f-part of W3, k=256..512)
  unsigned short *w4p;     // [8 mtile][64 kgg][128 cout_rel][8]
  unsigned short *fbufp;   // [1024 ntile][32 kgg][128 pt_rel][8]  (f acts, 256 ch)
  unsigned short *h3p;     // [1024 ntile][64 kgg][128 pt_rel][8]  (h3 acts, 512 ch)
  float* cseg;             // [16][512] = W3[:, :256] @ gs(seg)
  float* out;
};

__device__ inline unsigned int f2key(float f){ unsigned u=__float_as_uint(f); return (u&0x80000000u)? ~u : (u|0x80000000u); }
__device__ inline float key2f(unsigned k){ unsigned u=(k&0x80000000u)? (k^0x80000000u) : ~k; return __uint_as_float(u); }
__device__ inline unsigned short f2bf(float f){ __hip_bfloat16 h=__float2bfloat16(f); return *(unsigned short*)&h; }

__device__ inline void gl16(const void* g, void* l){
  __builtin_amdgcn_global_load_lds((const __attribute__((address_space(1))) unsigned int*)g,
                                   (__attribute__((address_space(3))) unsigned int*)l, 16, 0, 0);
}

// ---------------- setup ----------------
__global__ void k_setup(Args A){
  int tid = threadIdx.x;
  if (tid==0){ int s=0; A.offs[0]=0; for (int i=0;i<NSEG;i++){ s+=A.npts[i]; A.offs[i+1]=s; } }
  for (int c=tid;c<128;c+=256){ float a=A.g1[c]*rsqrtf(A.v1[c]+EPSV); A.a1[c]=a; A.c1[c]=A.be1[c]+a*(A.b1[c]-A.m1[c]); }
  for (int c=tid;c<256;c+=256){ float a=A.g2[c]*rsqrtf(A.v2[c]+EPSV); A.a2[c]=a; A.c2[c]=A.be2[c]+a*(A.b2[c]-A.m2[c]); }
  for (int c=tid;c<512;c+=256){ float a=A.g3[c]*rsqrtf(A.v3[c]+EPSV); A.a3[c]=a; A.c3[c]=A.be3[c]+a*(A.b3[c]-A.m3[c]); }
  for (int c=tid;c<1024;c+=256){ float a=A.g4[c]*rsqrtf(A.v4[c]+EPSV); A.a4[c]=a; A.c4[c]=A.be4[c]+a*(A.b4[c]-A.m4[c]); }
  for (int i=tid;i<NSEG*256;i+=256)  A.gkeys[i]=0u;
  for (int i=tid;i<NSEG*1024;i+=256) A.vkeys[i]=0u;
}

// ---------------- weights fp32 -> bf16, tile-packed for gl16 staging (round-2 packing) ----------------
// w3p[o]: o = mtile<<15 | kgg<<10 | cout_rel<<3 | j  -> W3[(mtile*128+cout_rel)*512 + 256 + kgg*8 + j]
// w4p[o]: o = mtile<<16 | kgg<<10 | cout_rel<<3 | j  -> W4[(mtile*128+cout_rel)*512 + kgg*8 + j]
__global__ void k_conv(Args A){
  const int n1=256*128;        // 32768
  const int n2=131072;
  const int n3=524288;
  for (int i = blockIdx.x*256+threadIdx.x; i < n1+n2+n3; i += gridDim.x*256){
    if (i<n1) A.w2b[i]=f2bf(A.W2[i]);
    else if (i<n1+n2){
      int o=i-n1; int j=o&7, cr=(o>>3)&127, kgg=(o>>10)&31, mt=o>>15;
      A.w3p[o]=f2bf(A.W3[(size_t)(mt*128+cr)*512 + 256 + kgg*8 + j]);
    } else {
      int o=i-n1-n2; int j=o&7, cr=(o>>3)&127, kgg=(o>>10)&63, mt=o>>16;
      A.w4p[o]=f2bf(A.W4[(size_t)(mt*128+cr)*512 + kgg*8 + j]);
    }
  }
}

// ---------------- L1 (VALU) + L2 (MFMA) + BN -> fbufp packed + gkeys (round-2 verbatim) ----------------
__global__ __launch_bounds__(256) void k_l12(Args A){
  __shared__ float w1s[384], a1s[128], c1s[128], a2s[256], c2s[256];
  __shared__ float xs[3][64];
  __shared__ int offs_s[NSEG+1], segp[64];
  __shared__ unsigned short hs[16*64*8];
  int tid=threadIdx.x, pt0=blockIdx.x*64;
  for (int i=tid;i<384;i+=256) w1s[i]=A.W1[i];
  if (tid<128){ a1s[tid]=A.a1[tid]; c1s[tid]=A.c1[tid]; }
  a2s[tid]=A.a2[tid]; c2s[tid]=A.c2[tid];
  if (tid<=NSEG) offs_s[tid]=A.offs[tid];
  if (tid<64){ xs[0][tid]=A.x[pt0+tid]; xs[1][tid]=A.x[NTOT+pt0+tid]; xs[2][tid]=A.x[2*NTOT+pt0+tid]; }
  __syncthreads();
  if (tid<64){ int gp=pt0+tid, s=0; while (gp>=offs_s[s+1]) s++; segp[tid]=s; }
  for (int pair=tid; pair<1024; pair+=256){
    int pt=pair&63, kc=pair>>6;
    float x0=xs[0][pt], x1=xs[1][pt], x2=xs[2][pt];
    unsigned short us[8];
    #pragma unroll
    for (int j=0;j<8;j++){
      int cin=kc*8+j;
      float v = fmaf(w1s[cin*3],x0, fmaf(w1s[cin*3+1],x1, w1s[cin*3+2]*x2));
      v = fmaxf(fmaf(a1s[cin],v,c1s[cin]), 0.f);
      us[j]=f2bf(v);
    }
    uint4 pk;
    pk.x=(unsigned)us[0]|((unsigned)us[1]<<16); pk.y=(unsigned)us[2]|((unsigned)us[3]<<16);
    pk.z=(unsigned)us[4]|((unsigned)us[5]<<16); pk.w=(unsigned)us[6]|((unsigned)us[7]<<16);
    *(uint4*)(&hs[(kc*64+pt)*8]) = pk;
  }
  __syncthreads();
  int lane=tid&63, wv=tid>>6, quad=lane>>4, l16=lane&15;
  int m0=wv*64;
  f32x4 acc[4][4];
  for (int a=0;a<4;a++)
    for (int b=0;b<4;b++)
      acc[a][b]=(f32x4){0.f,0.f,0.f,0.f};
  #pragma unroll
  for (int ks=0; ks<4; ++ks){
    bf16x8 bfr[4];
    #pragma unroll
    for (int nt=0; nt<4; ++nt) bfr[nt]=*(bf16x8*)(&hs[((ks*4+quad)*64 + nt*16 + l16)*8]);
    #pragma unroll
    for (int mt=0; mt<4; ++mt){
      bf16x8 afr = *(const bf16x8*)(&A.w2b[(m0+mt*16+l16)*128 + ks*32 + quad*8]);
      #pragma unroll
      for (int nt=0; nt<4; ++nt)
        acc[mt][nt]=__builtin_amdgcn_mfma_f32_16x16x32_bf16(afr, bfr[nt], acc[mt][nt], 0,0,0);
    }
  }
  bool uni = (segp[0]==segp[63]); int seg0=segp[0];
  size_t tb = (size_t)(blockIdx.x>>1)*32768;   // ntile base in fbufp entries
  int prelb = (blockIdx.x&1)*64;
  #pragma unroll
  for (int mt=0;mt<4;++mt){
    int cout0=m0+mt*16+quad*4;
    int kg=cout0>>3, sub=cout0&7;
    float fv[4][4];
    #pragma unroll
    for (int nt=0;nt<4;++nt)
      #pragma unroll
      for (int r=0;r<4;++r)
        fv[nt][r]=fmaf(a2s[cout0+r], acc[mt][nt][r], c2s[cout0+r]);
    #pragma unroll
    for (int nt=0;nt<4;++nt){
      int ptl=nt*16+l16;
      uint2 pk;
      pk.x=(unsigned)f2bf(fv[nt][0])|((unsigned)f2bf(fv[nt][1])<<16);
      pk.y=(unsigned)f2bf(fv[nt][2])|((unsigned)f2bf(fv[nt][3])<<16);
      *(uint2*)&A.fbufp[tb + (size_t)((kg*128 + prelb + ptl)*8 + sub)] = pk;
    }
    #pragma unroll
    for (int r=0;r<4;++r){
      if (uni){
        float mv=fmaxf(fmaxf(fv[0][r],fv[1][r]),fmaxf(fv[2][r],fv[3][r]));
        #pragma unroll
        for (int off=8;off>=1;off>>=1) mv=fmaxf(mv, __shfl_xor(mv,off));
        if (l16==0) atomicMax(&A.gkeys[seg0*256+cout0+r], f2key(mv));
      } else {
        #pragma unroll
        for (int nt=0;nt<4;++nt)
          atomicMax(&A.gkeys[segp[nt*16+l16]*256+cout0+r], f2key(fv[nt][r]));
      }
    }
  }
}

// ---------------- cseg[seg][cout] = W3[:, :256] @ gs(seg) ----------------
__global__ void k_cseg(Args A){
  int seg = blockIdx.x>>1; int cout = (blockIdx.x&1)*256 + threadIdx.x;
  __shared__ float gs[256];
  gs[threadIdx.x] = key2f(A.gkeys[seg*256+threadIdx.x]);
  __syncthreads();
  const float* wrow = A.W3 + (size_t)cout*512;
  float s=0.f;
  #pragma unroll 8
  for (int k=0;k<256;k++) s = fmaf(wrow[k], gs[k], s);
  A.cseg[seg*512+cout]=s;
}

// ---------------- L3: persistent blocks, fixed mtile, round-2 inner loop ----------------
// 1024 blocks (= 4/CU) x 256 thr. Block (m, slot): m = weight slice (L2-hot, fixed),
// slot picks ntile sequence slot + it*256; bid&7 == slot&7 so the 4 mtile-sharers of an
// ntile sit on one XCD at the same loop step -> B L2-hits after first fill.
__global__ __launch_bounds__(256,4) void k_l3(Args A){
  __shared__ unsigned short sA[8192], sB[8192];   // 16 KB each
  __shared__ int offs_s[NSEG+1];
  int bid=blockIdx.x, xcd=bid&7, g=bid>>3;        // g = m + 4*shi
  int m=g&3, shi=g>>2;                            // shi 0..31
  int slot = xcd + 8*shi;                         // 0..255
  int tid=threadIdx.x, lane=tid&63, wv=tid>>6, quad=lane>>4, l16=lane&15;
  int mq=wv&1, nq=wv>>1;
  const char* wbase=(const char*)A.w3p + (size_t)m*65536;   // 4 stages x 16 KB
  if (tid<=NSEG) offs_s[tid]=A.offs[tid];

  for (int it=0; it<4; ++it){
    int ntile = slot + it*256;
    const char* bbase=(const char*)A.fbufp + (size_t)ntile*65536;
    f32x4 acc[4][4];
    for (int a=0;a<4;a++)
      for (int b=0;b<4;b++)
        acc[a][b]=(f32x4){0.f,0.f,0.f,0.f};
    for (int s=0;s<4;++s){
      const char* srcA = wbase + s*16384;
      const char* srcB = bbase + s*16384;
      #pragma unroll
      for (int i=0;i<4;++i){
        gl16(srcA + wv*4096 + i*1024 + lane*16, (char*)sA + wv*4096 + i*1024);
        gl16(srcB + wv*4096 + i*1024 + lane*16, (char*)sB + wv*4096 + i*1024);
      }
      __syncthreads();
      #pragma unroll
      for (int ks=0;ks<2;++ks){
        bf16x8 bb[4], afr[4];
        #pragma unroll
        for (int nt=0;nt<4;++nt) bb[nt]=*(const bf16x8*)(&sB[((ks*4+quad)*128 + nq*64 + nt*16 + l16)*8]);
        #pragma unroll
        for (int mt=0;mt<4;++mt) afr[mt]=*(const bf16x8*)(&sA[((ks*4+quad)*128 + mq*64 + mt*16 + l16)*8]);
        #pragma unroll
        for (int mt=0;mt<4;++mt)
          #pragma unroll
          for (int nt=0;nt<4;++nt)
            acc[mt][nt]=__builtin_amdgcn_mfma_f32_16x16x32_bf16(afr[mt], bb[nt], acc[mt][nt], 0,0,0);
      }
      __syncthreads();
    }
    // epilogue: BN + ReLU + cseg add, pack to h3p (regs/global only; no LDS reads)
    int pt0 = ntile*128 + nq*64;
    int sBeg=0; while (pt0 >= offs_s[sBeg+1]) sBeg++;
    int sEnd=sBeg; while (pt0+63 >= offs_s[sEnd+1]) sEnd++;
    bool uni=(sBeg==sEnd);
    int segl[4];
    if (!uni){
      #pragma unroll
      for (int nt=0;nt<4;++nt){ int gp=pt0+nt*16+l16, ss=sBeg; while (gp>=offs_s[ss+1]) ss++; segl[nt]=ss; }
    }
    size_t hb = (size_t)ntile*65536;
    #pragma unroll
    for (int mt=0;mt<4;++mt){
      int cout0=m*128 + mq*64 + mt*16 + quad*4;
      int kg=cout0>>3, sub=cout0&7;
      float sa[4],sc[4],csr[4];
      #pragma unroll
      for (int r=0;r<4;++r){ sa[r]=A.a3[cout0+r]; sc[r]=A.c3[cout0+r]; }
      if (uni){
        #pragma unroll
        for (int r=0;r<4;++r) csr[r]=A.cseg[sBeg*512+cout0+r];
      }
      #pragma unroll
      for (int nt=0;nt<4;++nt){
        int prel=nq*64+nt*16+l16;
        unsigned short us[4];
        #pragma unroll
        for (int r=0;r<4;++r){
          float cv = uni? csr[r] : A.cseg[segl[nt]*512+cout0+r];
          float hv = fmaxf(fmaf(sa[r], acc[mt][nt][r]+cv, sc[r]), 0.f);
          us[r]=f2bf(hv);
        }
        uint2 pk;
        pk.x=(unsigned)us[0]|((unsigned)us[1]<<16);
        pk.y=(unsigned)us[2]|((unsigned)us[3]<<16);
        *(uint2*)&A.h3p[hb + (size_t)((kg*128+prel)*8+sub)] = pk;
      }
    }
  }
}

// ---------------- L4: persistent blocks, fixed mtile, round-2 inner loop, fused segmax ----------------
// 1024 blocks (= 4/CU) x 256 thr. Block (m, slot): m 0..7 fixed weight slice; slot 0..127;
// ntile = slot + it*128, it<8. bid&7 == slot&7 -> the 8 mtile-sharers of an ntile on one XCD.
__global__ __launch_bounds__(256,4) void k_l4(Args A){
  __shared__ unsigned short sA[8192], sB[8192];
  __shared__ int offs_s[NSEG+1];
  int bid=blockIdx.x, xcd=bid&7, g=bid>>3;        // g = m + 8*shi
  int m=g&7, shi=g>>3;                            // shi 0..15
  int slot = xcd + 8*shi;                         // 0..127
  int tid=threadIdx.x, lane=tid&63, wv=tid>>6, quad=lane>>4, l16=lane&15;
  int mq=wv&1, nq=wv>>1;
  const char* wbase=(const char*)A.w4p + (size_t)m*131072;   // 8 stages x 16 KB
  if (tid<=NSEG) offs_s[tid]=A.offs[tid];

  for (int it=0; it<8; ++it){
    int ntile = slot + it*128;
    const char* bbase=(const char*)A.h3p + (size_t)ntile*131072;
    f32x4 acc[4][4];
    for (int a=0;a<4;a++)
      for (int b=0;b<4;b++)
        acc[a][b]=(f32x4){0.f,0.f,0.f,0.f};
    for (int s=0;s<8;++s){
      const char* srcA = wbase + s*16384;
      const char* srcB = bbase + s*16384;
      #pragma unroll
      for (int i=0;i<4;++i){
        gl16(srcA + wv*4096 + i*1024 + lane*16, (char*)sA + wv*4096 + i*1024);
        gl16(srcB + wv*4096 + i*1024 + lane*16, (char*)sB + wv*4096 + i*1024);
      }
      __syncthreads();
      #pragma unroll
      for (int ks=0;ks<2;++ks){
        bf16x8 bb[4], afr[4];
        #pragma unroll
        for (int nt=0;nt<4;++nt) bb[nt]=*(const bf16x8*)(&sB[((ks*4+quad)*128 + nq*64 + nt*16 + l16)*8]);
        #pragma unroll
        for (int mt=0;mt<4;++mt) afr[mt]=*(const bf16x8*)(&sA[((ks*4+quad)*128 + mq*64 + mt*16 + l16)*8]);
        #pragma unroll
        for (int mt=0;mt<4;++mt)
          #pragma unroll
          for (int nt=0;nt<4;++nt)
            acc[mt][nt]=__builtin_amdgcn_mfma_f32_16x16x32_bf16(afr[mt], bb[nt], acc[mt][nt], 0,0,0);
      }
      __syncthreads();
    }
    // epilogue: BN + fused segmax (regs/global only)
    int pt0 = ntile*128 + nq*64;
    int sBeg=0; while (pt0 >= offs_s[sBeg+1]) sBeg++;
    int sEnd=sBeg; while (pt0+63 >= offs_s[sEnd+1]) sEnd++;
    bool uni=(sBeg==sEnd);
    int segl[4];
    if (!uni){
      #pragma unroll
      for (int nt=0;nt<4;++nt){ int gp=pt0+nt*16+l16, ss=sBeg; while (gp>=offs_s[ss+1]) ss++; segl[nt]=ss; }
    }
    #pragma unroll
    for (int mt=0;mt<4;++mt){
      int cout0=m*128 + mq*64 + mt*16 + quad*4;
      #pragma unroll
      for (int r=0;r<4;++r){
        int cout=cout0+r;
        float sa=A.a4[cout], sc=A.c4[cout];
        float mv=-3.4e38f;
        #pragma unroll
        for (int nt=0;nt<4;++nt){
          float fv=fmaf(sa, acc[mt][nt][r], sc);
          if (uni) mv=fmaxf(mv,fv);
          else atomicMax(&A.vkeys[segl[nt]*1024+cout], f2key(fv));
        }
        if (uni){
          #pragma unroll
          for (int off=8;off>=1;off>>=1) mv=fmaxf(mv, __shfl_xor(mv,off));
          if (l16==0) atomicMax(&A.vkeys[sBeg*1024+cout], f2key(mv));
        }
      }
    }
  }
}

// ---------------- decode ----------------
__global__ void k_final(Args A){
  int i=blockIdx.x*256+threadIdx.x;
  if (i<NSEG*1024) A.out[i]=key2f(A.vkeys[i]);
}

extern "C" void kernel_launch(void* const* d_in, const int* in_sizes, int n_in,
                              void* d_out, int out_size, void* d_ws, size_t ws_size,
                              hipStream_t stream){
  Args A;
  A.x  =(const float*)d_in[0];  A.npts=(const int*)d_in[1];
  A.W1 =(const float*)d_in[2];  A.b1 =(const float*)d_in[3];
  A.g1 =(const float*)d_in[4];  A.be1=(const float*)d_in[5];
  A.m1 =(const float*)d_in[6];  A.v1 =(const float*)d_in[7];
  A.W2 =(const float*)d_in[8];  A.b2 =(const float*)d_in[9];
  A.g2 =(const float*)d_in[10]; A.be2=(const float*)d_in[11];
  A.m2 =(const float*)d_in[12]; A.v2 =(const float*)d_in[13];
  A.W3 =(const float*)d_in[14]; A.b3 =(const float*)d_in[15];
  A.g3 =(const float*)d_in[16]; A.be3=(const float*)d_in[17];
  A.m3 =(const float*)d_in[18]; A.v3 =(const float*)d_in[19];
  A.W4 =(const float*)d_in[20]; A.b4 =(const float*)d_in[21];
  A.g4 =(const float*)d_in[22]; A.be4=(const float*)d_in[23];
  A.m4 =(const float*)d_in[24]; A.v4 =(const float*)d_in[25];

  char* w=(char*)d_ws;
  auto alloc=[&](size_t b)->void*{ void* p=(void*)w; w += (b+255)&~(size_t)255; return p; };
  A.offs =(int*)alloc((NSEG+1)*4);
  A.a1=(float*)alloc(128*4);  A.c1=(float*)alloc(128*4);
  A.a2=(float*)alloc(256*4);  A.c2=(float*)alloc(256*4);
  A.a3=(float*)alloc(512*4);  A.c3=(float*)alloc(512*4);
  A.a4=(float*)alloc(1024*4); A.c4=(float*)alloc(1024*4);
  A.gkeys=(unsigned int*)alloc(NSEG*256*4);
  A.vkeys=(unsigned int*)alloc(NSEG*1024*4);
  A.cseg =(float*)alloc(NSEG*512*4);
  A.w2b=(unsigned short*)alloc(256*128*2);
  A.w3p=(unsigned short*)alloc(131072*2);
  A.w4p=(unsigned short*)alloc(524288*2);
  A.fbufp=(unsigned short*)alloc((size_t)1024*32768*2);  // 64 MB
  A.h3p  =(unsigned short*)alloc((size_t)1024*65536*2);  // 128 MB
  A.out=(float*)d_out;

  k_setup<<<dim3(1),dim3(256),0,stream>>>(A);
  k_conv <<<dim3(2688),dim3(256),0,stream>>>(A);
  k_l12  <<<dim3(NTOT/64),dim3(256),0,stream>>>(A);
  k_cseg <<<dim3(32),dim3(256),0,stream>>>(A);
  k_l3   <<<dim3(1024),dim3(256),0,stream>>>(A);
  k_l4   <<<dim3(1024),dim3(256),0,stream>>>(A);
  k_final<<<dim3(64),dim3(256),0,stream>>>(A);
}

// Round 7
// 688.621 us; speedup vs baseline: 1.3554x; 1.1687x over previous
//
#include <hip/hip_runtime.h>
#include <hip/hip_bf16.h>
#include <stdint.h>

#define NTOT 131072
#define NSEG 16
#define EPSV 1e-5f

typedef __attribute__((ext_vector_type(8))) short bf16x8;
typedef __attribute__((ext_vector_type(4))) float f32x4;

struct Args {
  const float* x; const int* npts;
  const float *W1,*b1,*g1,*be1,*m1,*v1;
  const float *W2,*b2,*g2,*be2,*m2,*v2;
  const float *W3,*b3,*g3,*be3,*m3,*v3;
  const float *W4,*b4,*g4,*be4,*m4,*v4;
  int* offs;
  float *a1,*c1,*a2,*c2,*a3,*c3,*a4,*c4;
  unsigned int *gkeys,*vkeys;
  unsigned short *w2b;
  unsigned short *w3p;     // [4 mtile][32 kgg][128 cout_rel][8]   (f-part of W3, k=256..512)
  unsigned short *w4p;     // [8 mtile][64 kgg][128 cout_rel][8]
  unsigned short *fbufp;   // [1024 ntile][32 kgg][128 pt_rel][8]  (f acts, 256 ch)
  unsigned short *h3p;     // [1024 ntile][64 kgg][128 pt_rel][8]  (h3 acts, 512 ch)
  float* cseg;             // [16][512] = W3[:, :256] @ gs(seg)
  float* out;
};

__device__ inline unsigned int f2key(float f){ unsigned u=__float_as_uint(f); return (u&0x80000000u)? ~u : (u|0x80000000u); }
__device__ inline float key2f(unsigned k){ unsigned u=(k&0x80000000u)? (k^0x80000000u) : ~k; return __uint_as_float(u); }
__device__ inline unsigned short f2bf(float f){ __hip_bfloat16 h=__float2bfloat16(f); return *(unsigned short*)&h; }

__device__ inline void gl16(const void* g, void* l){
  __builtin_amdgcn_global_load_lds((const __attribute__((address_space(1))) unsigned int*)g,
                                   (__attribute__((address_space(3))) unsigned int*)l, 16, 0, 0);
}

// ---------------- setup ----------------
__global__ void k_setup(Args A){
  int tid = threadIdx.x;
  if (tid==0){ int s=0; A.offs[0]=0; for (int i=0;i<NSEG;i++){ s+=A.npts[i]; A.offs[i+1]=s; } }
  for (int c=tid;c<128;c+=256){ float a=A.g1[c]*rsqrtf(A.v1[c]+EPSV); A.a1[c]=a; A.c1[c]=A.be1[c]+a*(A.b1[c]-A.m1[c]); }
  for (int c=tid;c<256;c+=256){ float a=A.g2[c]*rsqrtf(A.v2[c]+EPSV); A.a2[c]=a; A.c2[c]=A.be2[c]+a*(A.b2[c]-A.m2[c]); }
  for (int c=tid;c<512;c+=256){ float a=A.g3[c]*rsqrtf(A.v3[c]+EPSV); A.a3[c]=a; A.c3[c]=A.be3[c]+a*(A.b3[c]-A.m3[c]); }
  for (int c=tid;c<1024;c+=256){ float a=A.g4[c]*rsqrtf(A.v4[c]+EPSV); A.a4[c]=a; A.c4[c]=A.be4[c]+a*(A.b4[c]-A.m4[c]); }
  for (int i=tid;i<NSEG*256;i+=256)  A.gkeys[i]=0u;
  for (int i=tid;i<NSEG*1024;i+=256) A.vkeys[i]=0u;
}

// ---------------- weights fp32 -> bf16, tile-packed (round-2 packing) ----------------
// w3p[o]: o = mtile<<15 | kgg<<10 | cout_rel<<3 | j  -> W3[(mtile*128+cout_rel)*512 + 256 + kgg*8 + j]
// w4p[o]: o = mtile<<16 | kgg<<10 | cout_rel<<3 | j  -> W4[(mtile*128+cout_rel)*512 + kgg*8 + j]
__global__ void k_conv(Args A){
  const int n1=256*128;        // 32768
  const int n2=131072;
  const int n3=524288;
  for (int i = blockIdx.x*256+threadIdx.x; i < n1+n2+n3; i += gridDim.x*256){
    if (i<n1) A.w2b[i]=f2bf(A.W2[i]);
    else if (i<n1+n2){
      int o=i-n1; int j=o&7, cr=(o>>3)&127, kgg=(o>>10)&31, mt=o>>15;
      A.w3p[o]=f2bf(A.W3[(size_t)(mt*128+cr)*512 + 256 + kgg*8 + j]);
    } else {
      int o=i-n1-n2; int j=o&7, cr=(o>>3)&127, kgg=(o>>10)&63, mt=o>>16;
      A.w4p[o]=f2bf(A.W4[(size_t)(mt*128+cr)*512 + kgg*8 + j]);
    }
  }
}

// ---------------- L1 (VALU) + L2 (MFMA) + BN -> fbufp packed + gkeys (round-2 verbatim) ----------------
__global__ __launch_bounds__(256) void k_l12(Args A){
  __shared__ float w1s[384], a1s[128], c1s[128], a2s[256], c2s[256];
  __shared__ float xs[3][64];
  __shared__ int offs_s[NSEG+1], segp[64];
  __shared__ unsigned short hs[16*64*8];
  int tid=threadIdx.x, pt0=blockIdx.x*64;
  for (int i=tid;i<384;i+=256) w1s[i]=A.W1[i];
  if (tid<128){ a1s[tid]=A.a1[tid]; c1s[tid]=A.c1[tid]; }
  a2s[tid]=A.a2[tid]; c2s[tid]=A.c2[tid];
  if (tid<=NSEG) offs_s[tid]=A.offs[tid];
  if (tid<64){ xs[0][tid]=A.x[pt0+tid]; xs[1][tid]=A.x[NTOT+pt0+tid]; xs[2][tid]=A.x[2*NTOT+pt0+tid]; }
  __syncthreads();
  if (tid<64){ int gp=pt0+tid, s=0; while (gp>=offs_s[s+1]) s++; segp[tid]=s; }
  for (int pair=tid; pair<1024; pair+=256){
    int pt=pair&63, kc=pair>>6;
    float x0=xs[0][pt], x1=xs[1][pt], x2=xs[2][pt];
    unsigned short us[8];
    #pragma unroll
    for (int j=0;j<8;j++){
      int cin=kc*8+j;
      float v = fmaf(w1s[cin*3],x0, fmaf(w1s[cin*3+1],x1, w1s[cin*3+2]*x2));
      v = fmaxf(fmaf(a1s[cin],v,c1s[cin]), 0.f);
      us[j]=f2bf(v);
    }
    uint4 pk;
    pk.x=(unsigned)us[0]|((unsigned)us[1]<<16); pk.y=(unsigned)us[2]|((unsigned)us[3]<<16);
    pk.z=(unsigned)us[4]|((unsigned)us[5]<<16); pk.w=(unsigned)us[6]|((unsigned)us[7]<<16);
    *(uint4*)(&hs[(kc*64+pt)*8]) = pk;
  }
  __syncthreads();
  int lane=tid&63, wv=tid>>6, quad=lane>>4, l16=lane&15;
  int m0=wv*64;
  f32x4 acc[4][4];
  for (int a=0;a<4;a++)
    for (int b=0;b<4;b++)
      acc[a][b]=(f32x4){0.f,0.f,0.f,0.f};
  #pragma unroll
  for (int ks=0; ks<4; ++ks){
    bf16x8 bfr[4];
    #pragma unroll
    for (int nt=0; nt<4; ++nt) bfr[nt]=*(bf16x8*)(&hs[((ks*4+quad)*64 + nt*16 + l16)*8]);
    #pragma unroll
    for (int mt=0; mt<4; ++mt){
      bf16x8 afr = *(const bf16x8*)(&A.w2b[(m0+mt*16+l16)*128 + ks*32 + quad*8]);
      #pragma unroll
      for (int nt=0; nt<4; ++nt)
        acc[mt][nt]=__builtin_amdgcn_mfma_f32_16x16x32_bf16(afr, bfr[nt], acc[mt][nt], 0,0,0);
    }
  }
  bool uni = (segp[0]==segp[63]); int seg0=segp[0];
  size_t tb = (size_t)(blockIdx.x>>1)*32768;   // ntile128 base in fbufp entries
  int prelb = (blockIdx.x&1)*64;
  #pragma unroll
  for (int mt=0;mt<4;++mt){
    int cout0=m0+mt*16+quad*4;
    int kg=cout0>>3, sub=cout0&7;
    float fv[4][4];
    #pragma unroll
    for (int nt=0;nt<4;++nt)
      #pragma unroll
      for (int r=0;r<4;++r)
        fv[nt][r]=fmaf(a2s[cout0+r], acc[mt][nt][r], c2s[cout0+r]);
    #pragma unroll
    for (int nt=0;nt<4;++nt){
      int ptl=nt*16+l16;
      uint2 pk;
      pk.x=(unsigned)f2bf(fv[nt][0])|((unsigned)f2bf(fv[nt][1])<<16);
      pk.y=(unsigned)f2bf(fv[nt][2])|((unsigned)f2bf(fv[nt][3])<<16);
      *(uint2*)&A.fbufp[tb + (size_t)((kg*128 + prelb + ptl)*8 + sub)] = pk;
    }
    #pragma unroll
    for (int r=0;r<4;++r){
      if (uni){
        float mv=fmaxf(fmaxf(fv[0][r],fv[1][r]),fmaxf(fv[2][r],fv[3][r]));
        #pragma unroll
        for (int off=8;off>=1;off>>=1) mv=fmaxf(mv, __shfl_xor(mv,off));
        if (l16==0) atomicMax(&A.gkeys[seg0*256+cout0+r], f2key(mv));
      } else {
        #pragma unroll
        for (int nt=0;nt<4;++nt)
          atomicMax(&A.gkeys[segp[nt*16+l16]*256+cout0+r], f2key(fv[nt][r]));
      }
    }
  }
}

// ---------------- cseg[seg][cout] = W3[:, :256] @ gs(seg) ----------------
__global__ void k_cseg(Args A){
  int seg = blockIdx.x>>1; int cout = (blockIdx.x&1)*256 + threadIdx.x;
  __shared__ float gs[256];
  gs[threadIdx.x] = key2f(A.gkeys[seg*256+threadIdx.x]);
  __syncthreads();
  const float* wrow = A.W3 + (size_t)cout*512;
  float s=0.f;
  #pragma unroll 8
  for (int k=0;k<256;k++) s = fmaf(wrow[k], gs[k], s);
  A.cseg[seg*512+cout]=s;
}

// ---------------- L3: 256 couts x 64 pts, B-only LDS (8 KB), A per-lane from L2 ----------------
// 4096 blocks x 256 thr. Mt = 256-cout half (2); ntile = 64-pt tile (2048).
// bid = xcd + 8*(Mt + 2*k): 2 Mt-sharers of an ntile co-XCD, temporally adjacent.
__global__ __launch_bounds__(256,4) void k_l3(Args A){
  __shared__ unsigned short sB[4096];   // [8 kggrel][64 pt][8] = 8 KB
  __shared__ int offs_s[NSEG+1];
  int bid=blockIdx.x, xcd=bid&7, j=bid>>3;
  int Mt=j&1, ntile=xcd+8*(j>>1);       // ntile 0..2047
  int tid=threadIdx.x, lane=tid&63, wv=tid>>6, quad=lane>>4, l16=lane&15;
  int half=ntile&1, nt128=ntile>>1;
  const char* bbase=(const char*)A.fbufp + (size_t)nt128*65536 + half*1024;
  if (tid<=NSEG) offs_s[tid]=A.offs[tid];
  int coutw = Mt*256 + wv*64;
  f32x4 acc[4][4];
  for (int a=0;a<4;a++)
    for (int b=0;b<4;b++)
      acc[a][b]=(f32x4){0.f,0.f,0.f,0.f};
  for (int s=0;s<4;++s){
    const char* sb = bbase + (size_t)(s*8)*2048;
    gl16(sb + (tid>>6)*2048 + (tid&63)*16, (char*)sB + tid*16);
    gl16(sb + (4+(tid>>6))*2048 + (tid&63)*16, (char*)sB + 4096 + tid*16);
    __syncthreads();
    #pragma unroll
    for (int ks=0;ks<2;++ks){
      bf16x8 bb[4], afr[4];
      #pragma unroll
      for (int nt=0;nt<4;++nt) bb[nt]=*(const bf16x8*)(&sB[((ks*4+quad)*64 + nt*16 + l16)*8]);
      #pragma unroll
      for (int mt=0;mt<4;++mt){
        int cout = coutw + mt*16 + l16;
        afr[mt]=*(const bf16x8*)(A.w3p + (size_t)((cout>>7)<<15) + ((s*8+ks*4+quad)<<10) + ((cout&127)<<3));
      }
      #pragma unroll
      for (int mt=0;mt<4;++mt)
        #pragma unroll
        for (int nt=0;nt<4;++nt)
          acc[mt][nt]=__builtin_amdgcn_mfma_f32_16x16x32_bf16(afr[mt], bb[nt], acc[mt][nt], 0,0,0);
    }
    __syncthreads();
  }
  // epilogue: BN + ReLU + cseg add, pack to h3p
  int pt0 = ntile*64;
  int sBeg=0; while (pt0 >= offs_s[sBeg+1]) sBeg++;
  int sEnd=sBeg; while (pt0+63 >= offs_s[sEnd+1]) sEnd++;
  bool uni=(sBeg==sEnd);
  int segl[4];
  if (!uni){
    #pragma unroll
    for (int nt=0;nt<4;++nt){ int gp=pt0+nt*16+l16, ss=sBeg; while (gp>=offs_s[ss+1]) ss++; segl[nt]=ss; }
  }
  size_t hb = (size_t)nt128*65536;
  #pragma unroll
  for (int mt=0;mt<4;++mt){
    int cout0=coutw + mt*16 + quad*4;
    int kg=cout0>>3, sub=cout0&7;
    float sa[4],sc[4],csr[4];
    #pragma unroll
    for (int r=0;r<4;++r){ sa[r]=A.a3[cout0+r]; sc[r]=A.c3[cout0+r]; }
    if (uni){
      #pragma unroll
      for (int r=0;r<4;++r) csr[r]=A.cseg[sBeg*512+cout0+r];
    }
    #pragma unroll
    for (int nt=0;nt<4;++nt){
      int prel=half*64 + nt*16+l16;
      unsigned short us[4];
      #pragma unroll
      for (int r=0;r<4;++r){
        float cv = uni? csr[r] : A.cseg[segl[nt]*512+cout0+r];
        float hv = fmaxf(fmaf(sa[r], acc[mt][nt][r]+cv, sc[r]), 0.f);
        us[r]=f2bf(hv);
      }
      uint2 pk;
      pk.x=(unsigned)us[0]|((unsigned)us[1]<<16);
      pk.y=(unsigned)us[2]|((unsigned)us[3]<<16);
      *(uint2*)&A.h3p[hb + (size_t)((kg*128+prel)*8+sub)] = pk;
    }
  }
}

// ---------------- L4: 256 couts x 64 pts, B-only LDS, A per-lane from L2, fused segmax ----------------
// 8192 blocks x 256 thr. Mt 0..3; ntile 0..2047. bid = xcd + 8*(Mt + 4*k).
__global__ __launch_bounds__(256,4) void k_l4(Args A){
  __shared__ unsigned short sB[4096];   // 8 KB
  __shared__ int offs_s[NSEG+1];
  int bid=blockIdx.x, xcd=bid&7, j=bid>>3;
  int Mt=j&3, ntile=xcd+8*(j>>2);       // ntile 0..2047
  int tid=threadIdx.x, lane=tid&63, wv=tid>>6, quad=lane>>4, l16=lane&15;
  int half=ntile&1, nt128=ntile>>1;
  const char* bbase=(const char*)A.h3p + (size_t)nt128*131072 + half*1024;
  if (tid<=NSEG) offs_s[tid]=A.offs[tid];
  int coutw = Mt*256 + wv*64;
  f32x4 acc[4][4];
  for (int a=0;a<4;a++)
    for (int b=0;b<4;b++)
      acc[a][b]=(f32x4){0.f,0.f,0.f,0.f};
  for (int s=0;s<8;++s){
    const char* sb = bbase + (size_t)(s*8)*2048;
    gl16(sb + (tid>>6)*2048 + (tid&63)*16, (char*)sB + tid*16);
    gl16(sb + (4+(tid>>6))*2048 + (tid&63)*16, (char*)sB + 4096 + tid*16);
    __syncthreads();
    #pragma unroll
    for (int ks=0;ks<2;++ks){
      bf16x8 bb[4], afr[4];
      #pragma unroll
      for (int nt=0;nt<4;++nt) bb[nt]=*(const bf16x8*)(&sB[((ks*4+quad)*64 + nt*16 + l16)*8]);
      #pragma unroll
      for (int mt=0;mt<4;++mt){
        int cout = coutw + mt*16 + l16;
        afr[mt]=*(const bf16x8*)(A.w4p + (size_t)((cout>>7)<<16) + ((s*8+ks*4+quad)<<10) + ((cout&127)<<3));
      }
      #pragma unroll
      for (int mt=0;mt<4;++mt)
        #pragma unroll
        for (int nt=0;nt<4;++nt)
          acc[mt][nt]=__builtin_amdgcn_mfma_f32_16x16x32_bf16(afr[mt], bb[nt], acc[mt][nt], 0,0,0);
    }
    __syncthreads();
  }
  // epilogue: BN + fused segmax
  int pt0 = ntile*64;
  int sBeg=0; while (pt0 >= offs_s[sBeg+1]) sBeg++;
  int sEnd=sBeg; while (pt0+63 >= offs_s[sEnd+1]) sEnd++;
  bool uni=(sBeg==sEnd);
  int segl[4];
  if (!uni){
    #pragma unroll
    for (int nt=0;nt<4;++nt){ int gp=pt0+nt*16+l16, ss=sBeg; while (gp>=offs_s[ss+1]) ss++; segl[nt]=ss; }
  }
  #pragma unroll
  for (int mt=0;mt<4;++mt){
    int cout0=coutw + mt*16 + quad*4;
    #pragma unroll
    for (int r=0;r<4;++r){
      int cout=cout0+r;
      float sa=A.a4[cout], sc=A.c4[cout];
      float mv=-3.4e38f;
      #pragma unroll
      for (int nt=0;nt<4;++nt){
        float fv=fmaf(sa, acc[mt][nt][r], sc);
        if (uni) mv=fmaxf(mv,fv);
        else atomicMax(&A.vkeys[segl[nt]*1024+cout], f2key(fv));
      }
      if (uni){
        #pragma unroll
        for (int off=8;off>=1;off>>=1) mv=fmaxf(mv, __shfl_xor(mv,off));
        if (l16==0) atomicMax(&A.vkeys[sBeg*1024+cout], f2key(mv));
      }
    }
  }
}

// ---------------- decode ----------------
__global__ void k_final(Args A){
  int i=blockIdx.x*256+threadIdx.x;
  if (i<NSEG*1024) A.out[i]=key2f(A.vkeys[i]);
}

extern "C" void kernel_launch(void* const* d_in, const int* in_sizes, int n_in,
                              void* d_out, int out_size, void* d_ws, size_t ws_size,
                              hipStream_t stream){
  Args A;
  A.x  =(const float*)d_in[0];  A.npts=(const int*)d_in[1];
  A.W1 =(const float*)d_in[2];  A.b1 =(const float*)d_in[3];
  A.g1 =(const float*)d_in[4];  A.be1=(const float*)d_in[5];
  A.m1 =(const float*)d_in[6];  A.v1 =(const float*)d_in[7];
  A.W2 =(const float*)d_in[8];  A.b2 =(const float*)d_in[9];
  A.g2 =(const float*)d_in[10]; A.be2=(const float*)d_in[11];
  A.m2 =(const float*)d_in[12]; A.v2 =(const float*)d_in[13];
  A.W3 =(const float*)d_in[14]; A.b3 =(const float*)d_in[15];
  A.g3 =(const float*)d_in[16]; A.be3=(const float*)d_in[17];
  A.m3 =(const float*)d_in[18]; A.v3 =(const float*)d_in[19];
  A.W4 =(const float*)d_in[20]; A.b4 =(const float*)d_in[21];
  A.g4 =(const float*)d_in[22]; A.be4=(const float*)d_in[23];
  A.m4 =(const float*)d_in[24]; A.v4 =(const float*)d_in[25];

  char* w=(char*)d_ws;
  auto alloc=[&](size_t b)->void*{ void* p=(void*)w; w += (b+255)&~(size_t)255; return p; };
  A.offs =(int*)alloc((NSEG+1)*4);
  A.a1=(float*)alloc(128*4);  A.c1=(float*)alloc(128*4);
  A.a2=(float*)alloc(256*4);  A.c2=(float*)alloc(256*4);
  A.a3=(float*)alloc(512*4);  A.c3=(float*)alloc(512*4);
  A.a4=(float*)alloc(1024*4); A.c4=(float*)alloc(1024*4);
  A.gkeys=(unsigned int*)alloc(NSEG*256*4);
  A.vkeys=(unsigned int*)alloc(NSEG*1024*4);
  A.cseg =(float*)alloc(NSEG*512*4);
  A.w2b=(unsigned short*)alloc(256*128*2);
  A.w3p=(unsigned short*)alloc(131072*2);
  A.w4p=(unsigned short*)alloc(524288*2);
  A.fbufp=(unsigned short*)alloc((size_t)1024*32768*2);  // 64 MB
  A.h3p  =(unsigned short*)alloc((size_t)1024*65536*2);  // 128 MB
  A.out=(float*)d_out;

  k_setup<<<dim3(1),dim3(256),0,stream>>>(A);
  k_conv <<<dim3(2688),dim3(256),0,stream>>>(A);
  k_l12  <<<dim3(NTOT/64),dim3(256),0,stream>>>(A);
  k_cseg <<<dim3(32),dim3(256),0,stream>>>(A);
  k_l3   <<<dim3(4096),dim3(256),0,stream>>>(A);
  k_l4   <<<dim3(8192),dim3(256),0,stream>>>(A);
  k_final<<<dim3(64),dim3(256),0,stream>>>(A);
}

// Round 8
// 620.721 us; speedup vs baseline: 1.5036x; 1.1094x over previous
//
#include <hip/hip_runtime.h>
#include <hip/hip_bf16.h>
#include <stdint.h>

#define NTOT 131072
#define NSEG 16
#define EPSV 1e-5f

typedef __attribute__((ext_vector_type(8))) short bf16x8;
typedef __attribute__((ext_vector_type(4))) float f32x4;

struct Args {
  const float* x; const int* npts;
  const float *W1,*b1,*g1,*be1,*m1,*v1;
  const float *W2,*b2,*g2,*be2,*m2,*v2;
  const float *W3,*b3,*g3,*be3,*m3,*v3;
  const float *W4,*b4,*g4,*be4,*m4,*v4;
  int* offs;
  float *a1,*c1,*a2,*c2,*a3,*c3,*a4,*c4;
  unsigned int *gkeys,*vkeys;
  unsigned short *w2b;
  unsigned short *w3p;     // [2 Mt][4 kt][8 kgg][256 cr][8]  (f-part of W3, k=256..512), 32KB/(Mt,kt)
  unsigned short *w4p;     // [4 Mt][8 kt][8 kgg][256 cr][8], 32KB/(Mt,kt)
  unsigned short *fbufp;   // [1024 ntile][32 kgg][128 pt_rel][8]  (f acts, 256 ch)
  unsigned short *h3p;     // [1024 ntile][64 kgg][128 pt_rel][8]  (h3 acts, 512 ch)
  float* cseg;             // [16][512] = W3[:, :256] @ gs(seg)
  float* out;
};

__device__ inline unsigned int f2key(float f){ unsigned u=__float_as_uint(f); return (u&0x80000000u)? ~u : (u|0x80000000u); }
__device__ inline float key2f(unsigned k){ unsigned u=(k&0x80000000u)? (k^0x80000000u) : ~k; return __uint_as_float(u); }
__device__ inline unsigned short f2bf(float f){ __hip_bfloat16 h=__float2bfloat16(f); return *(unsigned short*)&h; }

__device__ inline void gl16(const void* g, void* l){
  __builtin_amdgcn_global_load_lds((const __attribute__((address_space(1))) unsigned int*)g,
                                   (__attribute__((address_space(3))) unsigned int*)l, 16, 0, 0);
}

// ---------------- setup ----------------
__global__ void k_setup(Args A){
  int tid = threadIdx.x;
  if (tid==0){ int s=0; A.offs[0]=0; for (int i=0;i<NSEG;i++){ s+=A.npts[i]; A.offs[i+1]=s; } }
  for (int c=tid;c<128;c+=256){ float a=A.g1[c]*rsqrtf(A.v1[c]+EPSV); A.a1[c]=a; A.c1[c]=A.be1[c]+a*(A.b1[c]-A.m1[c]); }
  for (int c=tid;c<256;c+=256){ float a=A.g2[c]*rsqrtf(A.v2[c]+EPSV); A.a2[c]=a; A.c2[c]=A.be2[c]+a*(A.b2[c]-A.m2[c]); }
  for (int c=tid;c<512;c+=256){ float a=A.g3[c]*rsqrtf(A.v3[c]+EPSV); A.a3[c]=a; A.c3[c]=A.be3[c]+a*(A.b3[c]-A.m3[c]); }
  for (int c=tid;c<1024;c+=256){ float a=A.g4[c]*rsqrtf(A.v4[c]+EPSV); A.a4[c]=a; A.c4[c]=A.be4[c]+a*(A.b4[c]-A.m4[c]); }
  for (int i=tid;i<NSEG*256;i+=256)  A.gkeys[i]=0u;
  for (int i=tid;i<NSEG*1024;i+=256) A.vkeys[i]=0u;
}

// ---------------- weights fp32 -> bf16, stage-chunk packed (32KB per (Mt,kt)) ----------------
// w3p[o]: o=(((Mt*4+kt)*8+kgg)*256+cr)*8+j -> W3[(Mt*256+cr)*512 + 256 + kt*64 + kgg*8 + j]
// w4p[o]: o=(((Mt*8+kt)*8+kgg)*256+cr)*8+j -> W4[(Mt*256+cr)*512 + kt*64 + kgg*8 + j]
__global__ void k_conv(Args A){
  const int n1=256*128;        // 32768
  const int n2=131072;
  const int n3=524288;
  for (int i = blockIdx.x*256+threadIdx.x; i < n1+n2+n3; i += gridDim.x*256){
    if (i<n1) A.w2b[i]=f2bf(A.W2[i]);
    else if (i<n1+n2){
      int o=i-n1; int j=o&7, cr=(o>>3)&255; int g=o>>11; int kgg=g&7, kt=(g>>3)&3, Mt=g>>5;
      A.w3p[o]=f2bf(A.W3[(size_t)(Mt*256+cr)*512 + 256 + kt*64 + kgg*8 + j]);
    } else {
      int o=i-n1-n2; int j=o&7, cr=(o>>3)&255; int g=o>>11; int kgg=g&7, kt=(g>>3)&7, Mt=g>>6;
      A.w4p[o]=f2bf(A.W4[(size_t)(Mt*256+cr)*512 + kt*64 + kgg*8 + j]);
    }
  }
}

// ---------------- L1 (VALU) + L2 (MFMA) + BN -> fbufp packed + gkeys (round-2 verbatim) ----------------
__global__ __launch_bounds__(256) void k_l12(Args A){
  __shared__ float w1s[384], a1s[128], c1s[128], a2s[256], c2s[256];
  __shared__ float xs[3][64];
  __shared__ int offs_s[NSEG+1], segp[64];
  __shared__ unsigned short hs[16*64*8];
  int tid=threadIdx.x, pt0=blockIdx.x*64;
  for (int i=tid;i<384;i+=256) w1s[i]=A.W1[i];
  if (tid<128){ a1s[tid]=A.a1[tid]; c1s[tid]=A.c1[tid]; }
  a2s[tid]=A.a2[tid]; c2s[tid]=A.c2[tid];
  if (tid<=NSEG) offs_s[tid]=A.offs[tid];
  if (tid<64){ xs[0][tid]=A.x[pt0+tid]; xs[1][tid]=A.x[NTOT+pt0+tid]; xs[2][tid]=A.x[2*NTOT+pt0+tid]; }
  __syncthreads();
  if (tid<64){ int gp=pt0+tid, s=0; while (gp>=offs_s[s+1]) s++; segp[tid]=s; }
  for (int pair=tid; pair<1024; pair+=256){
    int pt=pair&63, kc=pair>>6;
    float x0=xs[0][pt], x1=xs[1][pt], x2=xs[2][pt];
    unsigned short us[8];
    #pragma unroll
    for (int j=0;j<8;j++){
      int cin=kc*8+j;
      float v = fmaf(w1s[cin*3],x0, fmaf(w1s[cin*3+1],x1, w1s[cin*3+2]*x2));
      v = fmaxf(fmaf(a1s[cin],v,c1s[cin]), 0.f);
      us[j]=f2bf(v);
    }
    uint4 pk;
    pk.x=(unsigned)us[0]|((unsigned)us[1]<<16); pk.y=(unsigned)us[2]|((unsigned)us[3]<<16);
    pk.z=(unsigned)us[4]|((unsigned)us[5]<<16); pk.w=(unsigned)us[6]|((unsigned)us[7]<<16);
    *(uint4*)(&hs[(kc*64+pt)*8]) = pk;
  }
  __syncthreads();
  int lane=tid&63, wv=tid>>6, quad=lane>>4, l16=lane&15;
  int m0=wv*64;
  f32x4 acc[4][4];
  for (int a=0;a<4;a++)
    for (int b=0;b<4;b++)
      acc[a][b]=(f32x4){0.f,0.f,0.f,0.f};
  #pragma unroll
  for (int ks=0; ks<4; ++ks){
    bf16x8 bfr[4];
    #pragma unroll
    for (int nt=0; nt<4; ++nt) bfr[nt]=*(bf16x8*)(&hs[((ks*4+quad)*64 + nt*16 + l16)*8]);
    #pragma unroll
    for (int mt=0; mt<4; ++mt){
      bf16x8 afr = *(const bf16x8*)(&A.w2b[(m0+mt*16+l16)*128 + ks*32 + quad*8]);
      #pragma unroll
      for (int nt=0; nt<4; ++nt)
        acc[mt][nt]=__builtin_amdgcn_mfma_f32_16x16x32_bf16(afr, bfr[nt], acc[mt][nt], 0,0,0);
    }
  }
  bool uni = (segp[0]==segp[63]); int seg0=segp[0];
  size_t tb = (size_t)(blockIdx.x>>1)*32768;   // ntile128 base in fbufp entries
  int prelb = (blockIdx.x&1)*64;
  #pragma unroll
  for (int mt=0;mt<4;++mt){
    int cout0=m0+mt*16+quad*4;
    int kg=cout0>>3, sub=cout0&7;
    float fv[4][4];
    #pragma unroll
    for (int nt=0;nt<4;++nt)
      #pragma unroll
      for (int r=0;r<4;++r)
        fv[nt][r]=fmaf(a2s[cout0+r], acc[mt][nt][r], c2s[cout0+r]);
    #pragma unroll
    for (int nt=0;nt<4;++nt){
      int ptl=nt*16+l16;
      uint2 pk;
      pk.x=(unsigned)f2bf(fv[nt][0])|((unsigned)f2bf(fv[nt][1])<<16);
      pk.y=(unsigned)f2bf(fv[nt][2])|((unsigned)f2bf(fv[nt][3])<<16);
      *(uint2*)&A.fbufp[tb + (size_t)((kg*128 + prelb + ptl)*8 + sub)] = pk;
    }
    #pragma unroll
    for (int r=0;r<4;++r){
      if (uni){
        float mv=fmaxf(fmaxf(fv[0][r],fv[1][r]),fmaxf(fv[2][r],fv[3][r]));
        #pragma unroll
        for (int off=8;off>=1;off>>=1) mv=fmaxf(mv, __shfl_xor(mv,off));
        if (l16==0) atomicMax(&A.gkeys[seg0*256+cout0+r], f2key(mv));
      } else {
        #pragma unroll
        for (int nt=0;nt<4;++nt)
          atomicMax(&A.gkeys[segp[nt*16+l16]*256+cout0+r], f2key(fv[nt][r]));
      }
    }
  }
}

// ---------------- cseg[seg][cout] = W3[:, :256] @ gs(seg) ----------------
__global__ void k_cseg(Args A){
  int seg = blockIdx.x>>1; int cout = (blockIdx.x&1)*256 + threadIdx.x;
  __shared__ float gs[256];
  gs[threadIdx.x] = key2f(A.gkeys[seg*256+threadIdx.x]);
  __syncthreads();
  const float* wrow = A.W3 + (size_t)cout*512;
  float s=0.f;
  #pragma unroll 8
  for (int k=0;k<256;k++) s = fmaf(wrow[k], gs[k], s);
  A.cseg[seg*512+cout]=s;
}

// ---------------- L3: 256 couts x 128 pts, single-buffer 48KB LDS, round-2 loop ----------------
// 2048 blocks x 512 thr (8 waves 4Mx2N). Mt in {0,1}; ntile = xcd*128 + (idx>>1):
// the 2 Mt-sharers of each ntile land on one XCD, 16 bids apart.
__global__ __launch_bounds__(512,2) void k_l3(Args A){
  __shared__ unsigned short sA[16384], sB[8192];   // 32 KB + 16 KB
  __shared__ int offs_s[NSEG+1];
  int bid=blockIdx.x, xcd=bid&7, idx=bid>>3;
  int Mt=idx&1, ntile=xcd*128+(idx>>1);
  int tid=threadIdx.x, lane=tid&63, wv=tid>>6, quad=lane>>4, l16=lane&15;
  int wm=wv>>1, wn=wv&1;
  const char* wbase=(const char*)A.w3p   + (size_t)Mt*131072;   // 4 stages x 32 KB
  const char* bbase=(const char*)A.fbufp + (size_t)ntile*65536; // 4 stages x 16 KB
  if (tid<=NSEG) offs_s[tid]=A.offs[tid];
  f32x4 acc[4][4];
  for (int a=0;a<4;a++)
    for (int b=0;b<4;b++)
      acc[a][b]=(f32x4){0.f,0.f,0.f,0.f};
  for (int s=0;s<4;++s){
    const char* srcA = wbase + s*32768;
    const char* srcB = bbase + s*16384;
    #pragma unroll
    for (int i=0;i<4;++i)
      gl16(srcA + wv*4096 + i*1024 + lane*16, (char*)sA + wv*4096 + i*1024);
    #pragma unroll
    for (int i=0;i<2;++i)
      gl16(srcB + wv*2048 + i*1024 + lane*16, (char*)sB + wv*2048 + i*1024);
    __syncthreads();
    #pragma unroll
    for (int ks=0;ks<2;++ks){
      bf16x8 bb[4], afr[4];
      #pragma unroll
      for (int nt=0;nt<4;++nt) bb[nt]=*(const bf16x8*)(&sB[((ks*4+quad)*128 + wn*64 + nt*16 + l16)*8]);
      #pragma unroll
      for (int mt=0;mt<4;++mt) afr[mt]=*(const bf16x8*)(&sA[((ks*4+quad)*256 + wm*64 + mt*16 + l16)*8]);
      #pragma unroll
      for (int mt=0;mt<4;++mt)
        #pragma unroll
        for (int nt=0;nt<4;++nt)
          acc[mt][nt]=__builtin_amdgcn_mfma_f32_16x16x32_bf16(afr[mt], bb[nt], acc[mt][nt], 0,0,0);
    }
    __syncthreads();
  }
  // epilogue: BN + ReLU + cseg add, pack to h3p
  int pt0 = ntile*128 + wn*64;
  int sBeg=0; while (pt0 >= offs_s[sBeg+1]) sBeg++;
  int sEnd=sBeg; while (pt0+63 >= offs_s[sEnd+1]) sEnd++;
  bool uni=(sBeg==sEnd);
  int segl[4];
  if (!uni){
    #pragma unroll
    for (int nt=0;nt<4;++nt){ int gp=pt0+nt*16+l16, ss=sBeg; while (gp>=offs_s[ss+1]) ss++; segl[nt]=ss; }
  }
  size_t hb = (size_t)ntile*65536;
  #pragma unroll
  for (int mt=0;mt<4;++mt){
    int cout0=Mt*256 + wm*64 + mt*16 + quad*4;
    int kg=cout0>>3, sub=cout0&7;
    float sa[4],sc[4],csr[4];
    #pragma unroll
    for (int r=0;r<4;++r){ sa[r]=A.a3[cout0+r]; sc[r]=A.c3[cout0+r]; }
    if (uni){
      #pragma unroll
      for (int r=0;r<4;++r) csr[r]=A.cseg[sBeg*512+cout0+r];
    }
    #pragma unroll
    for (int nt=0;nt<4;++nt){
      int prel=wn*64+nt*16+l16;
      unsigned short us[4];
      #pragma unroll
      for (int r=0;r<4;++r){
        float cv = uni? csr[r] : A.cseg[segl[nt]*512+cout0+r];
        float hv = fmaxf(fmaf(sa[r], acc[mt][nt][r]+cv, sc[r]), 0.f);
        us[r]=f2bf(hv);
      }
      uint2 pk;
      pk.x=(unsigned)us[0]|((unsigned)us[1]<<16);
      pk.y=(unsigned)us[2]|((unsigned)us[3]<<16);
      *(uint2*)&A.h3p[hb + (size_t)((kg*128+prel)*8+sub)] = pk;
    }
  }
}

// ---------------- L4: 256 couts x 128 pts, single-buffer 48KB LDS, fused segmax ----------------
// 4096 blocks x 512 thr (8 waves 4Mx2N). Mt 0..3; ntile = xcd*128 + (idx>>2):
// the 4 Mt-sharers of each ntile on one XCD, 32 bids apart.
__global__ __launch_bounds__(512,2) void k_l4(Args A){
  __shared__ unsigned short sA[16384], sB[8192];   // 32 KB + 16 KB
  __shared__ int offs_s[NSEG+1];
  int bid=blockIdx.x, xcd=bid&7, idx=bid>>3;
  int Mt=idx&3, ntile=xcd*128+(idx>>2);
  int tid=threadIdx.x, lane=tid&63, wv=tid>>6, quad=lane>>4, l16=lane&15;
  int wm=wv>>1, wn=wv&1;
  const char* wbase=(const char*)A.w4p + (size_t)Mt*262144;    // 8 stages x 32 KB
  const char* bbase=(const char*)A.h3p + (size_t)ntile*131072; // 8 stages x 16 KB
  if (tid<=NSEG) offs_s[tid]=A.offs[tid];
  f32x4 acc[4][4];
  for (int a=0;a<4;a++)
    for (int b=0;b<4;b++)
      acc[a][b]=(f32x4){0.f,0.f,0.f,0.f};
  for (int s=0;s<8;++s){
    const char* srcA = wbase + s*32768;
    const char* srcB = bbase + s*16384;
    #pragma unroll
    for (int i=0;i<4;++i)
      gl16(srcA + wv*4096 + i*1024 + lane*16, (char*)sA + wv*4096 + i*1024);
    #pragma unroll
    for (int i=0;i<2;++i)
      gl16(srcB + wv*2048 + i*1024 + lane*16, (char*)sB + wv*2048 + i*1024);
    __syncthreads();
    #pragma unroll
    for (int ks=0;ks<2;++ks){
      bf16x8 bb[4], afr[4];
      #pragma unroll
      for (int nt=0;nt<4;++nt) bb[nt]=*(const bf16x8*)(&sB[((ks*4+quad)*128 + wn*64 + nt*16 + l16)*8]);
      #pragma unroll
      for (int mt=0;mt<4;++mt) afr[mt]=*(const bf16x8*)(&sA[((ks*4+quad)*256 + wm*64 + mt*16 + l16)*8]);
      #pragma unroll
      for (int mt=0;mt<4;++mt)
        #pragma unroll
        for (int nt=0;nt<4;++nt)
          acc[mt][nt]=__builtin_amdgcn_mfma_f32_16x16x32_bf16(afr[mt], bb[nt], acc[mt][nt], 0,0,0);
    }
    __syncthreads();
  }
  // epilogue: BN + fused segmax
  int pt0 = ntile*128 + wn*64;
  int sBeg=0; while (pt0 >= offs_s[sBeg+1]) sBeg++;
  int sEnd=sBeg; while (pt0+63 >= offs_s[sEnd+1]) sEnd++;
  bool uni=(sBeg==sEnd);
  int segl[4];
  if (!uni){
    #pragma unroll
    for (int nt=0;nt<4;++nt){ int gp=pt0+nt*16+l16, ss=sBeg; while (gp>=offs_s[ss+1]) ss++; segl[nt]=ss; }
  }
  #pragma unroll
  for (int mt=0;mt<4;++mt){
    int cout0=Mt*256 + wm*64 + mt*16 + quad*4;
    #pragma unroll
    for (int r=0;r<4;++r){
      int cout=cout0+r;
      float sa=A.a4[cout], sc=A.c4[cout];
      float mv=-3.4e38f;
      #pragma unroll
      for (int nt=0;nt<4;++nt){
        float fv=fmaf(sa, acc[mt][nt][r], sc);
        if (uni) mv=fmaxf(mv,fv);
        else atomicMax(&A.vkeys[segl[nt]*1024+cout], f2key(fv));
      }
      if (uni){
        #pragma unroll
        for (int off=8;off>=1;off>>=1) mv=fmaxf(mv, __shfl_xor(mv,off));
        if (l16==0) atomicMax(&A.vkeys[sBeg*1024+cout], f2key(mv));
      }
    }
  }
}

// ---------------- decode ----------------
__global__ void k_final(Args A){
  int i=blockIdx.x*256+threadIdx.x;
  if (i<NSEG*1024) A.out[i]=key2f(A.vkeys[i]);
}

extern "C" void kernel_launch(void* const* d_in, const int* in_sizes, int n_in,
                              void* d_out, int out_size, void* d_ws, size_t ws_size,
                              hipStream_t stream){
  Args A;
  A.x  =(const float*)d_in[0];  A.npts=(const int*)d_in[1];
  A.W1 =(const float*)d_in[2];  A.b1 =(const float*)d_in[3];
  A.g1 =(const float*)d_in[4];  A.be1=(const float*)d_in[5];
  A.m1 =(const float*)d_in[6];  A.v1 =(const float*)d_in[7];
  A.W2 =(const float*)d_in[8];  A.b2 =(const float*)d_in[9];
  A.g2 =(const float*)d_in[10]; A.be2=(const float*)d_in[11];
  A.m2 =(const float*)d_in[12]; A.v2 =(const float*)d_in[13];
  A.W3 =(const float*)d_in[14]; A.b3 =(const float*)d_in[15];
  A.g3 =(const float*)d_in[16]; A.be3=(const float*)d_in[17];
  A.m3 =(const float*)d_in[18]; A.v3 =(const float*)d_in[19];
  A.W4 =(const float*)d_in[20]; A.b4 =(const float*)d_in[21];
  A.g4 =(const float*)d_in[22]; A.be4=(const float*)d_in[23];
  A.m4 =(const float*)d_in[24]; A.v4 =(const float*)d_in[25];

  char* w=(char*)d_ws;
  auto alloc=[&](size_t b)->void*{ void* p=(void*)w; w += (b+255)&~(size_t)255; return p; };
  A.offs =(int*)alloc((NSEG+1)*4);
  A.a1=(float*)alloc(128*4);  A.c1=(float*)alloc(128*4);
  A.a2=(float*)alloc(256*4);  A.c2=(float*)alloc(256*4);
  A.a3=(float*)alloc(512*4);  A.c3=(float*)alloc(512*4);
  A.a4=(float*)alloc(1024*4); A.c4=(float*)alloc(1024*4);
  A.gkeys=(unsigned int*)alloc(NSEG*256*4);
  A.vkeys=(unsigned int*)alloc(NSEG*1024*4);
  A.cseg =(float*)alloc(NSEG*512*4);
  A.w2b=(unsigned short*)alloc(256*128*2);
  A.w3p=(unsigned short*)alloc(131072*2);
  A.w4p=(unsigned short*)alloc(524288*2);
  A.fbufp=(unsigned short*)alloc((size_t)1024*32768*2);  // 64 MB
  A.h3p  =(unsigned short*)alloc((size_t)1024*65536*2);  // 128 MB
  A.out=(float*)d_out;

  k_setup<<<dim3(1),dim3(256),0,stream>>>(A);
  k_conv <<<dim3(2688),dim3(256),0,stream>>>(A);
  k_l12  <<<dim3(NTOT/64),dim3(256),0,stream>>>(A);
  k_cseg <<<dim3(32),dim3(256),0,stream>>>(A);
  k_l3   <<<dim3(2048),dim3(512),0,stream>>>(A);
  k_l4   <<<dim3(4096),dim3(512),0,stream>>>(A);
  k_final<<<dim3(64),dim3(256),0,stream>>>(A);
}